// Round 12
// baseline (564.568 us; speedup 1.0000x reference)
//
#include <hip/hip_runtime.h>
#include <hip/hip_bf16.h>

#define E_EDGES 500000
#define NN 50000

typedef unsigned short u16;
typedef __attribute__((ext_vector_type(8))) short s16x8;
typedef __attribute__((ext_vector_type(4))) float f32x4;

#define BAR() __builtin_amdgcn_s_barrier()
#define SCHED0() __builtin_amdgcn_sched_barrier(0)
#define WAITLGKM0() asm volatile("s_waitcnt lgkmcnt(0)" ::: "memory")

__device__ __forceinline__ short f2bf(float f) {
    unsigned u = __builtin_bit_cast(unsigned, f);
    u += 0x7fffu + ((u >> 16) & 1u);
    return (short)(u >> 16);
}

__device__ __forceinline__ float lrelu(float x) { return x > 0.0f ? x : 0.01f * x; }

// packed fp32x8 -> bf16x8 via v_cvt_pk_bf16_f32
__device__ __forceinline__ s16x8 cvt8(float4 lo, float4 hi) {
    union { s16x8 v; __hip_bfloat162 h[4]; } u;
    u.h[0] = __float22bfloat162_rn(make_float2(lo.x, lo.y));
    u.h[1] = __float22bfloat162_rn(make_float2(lo.z, lo.w));
    u.h[2] = __float22bfloat162_rn(make_float2(hi.x, hi.y));
    u.h[3] = __float22bfloat162_rn(make_float2(hi.z, hi.w));
    return u.v;
}

// ---- weight prep: WT[g][n][k] = bf16(W_g[k][n]), g in {src, tgt, edge} ----
__global__ void kprep(const float* __restrict__ Wsrc, const float* __restrict__ Wtgt,
                      const float* __restrict__ Wedge, u16* __restrict__ WT) {
    int i = blockIdx.x * 256 + threadIdx.x;
    if (i >= 3 * 16384) return;
    int g = i >> 14, nk = i & 16383, n = nk >> 7, k = nk & 127;
    const float* W = (g == 0) ? Wsrc : (g == 1) ? Wtgt : Wedge;
    WT[i] = (u16)f2bf(W[k * 128 + n]);
}

// ---- K1: M=64 tile, phase-overlap staging, NO ldsB (B per-lane from L1/L2).
// LDS 18.4 KB, ~100 VGPR -> target 4 blocks/CU (16 waves). ----
__global__ __launch_bounds__(256, 2) void k1(
    const float* __restrict__ recv, const float* __restrict__ send,
    const float* __restrict__ eattr, const int* __restrict__ sidx,
    const u16* __restrict__ WT, const float* __restrict__ attn,
    float* __restrict__ ez, float* __restrict__ denom)
{
    __shared__ u16 ldsA[64][136];      // 17408 B
    __shared__ float smEz[4][16][4];   // 1 KB, wave-private
    const int tid = threadIdx.x;
    const int lane = tid & 63, wv = tid >> 6;        // 4 waves, 16 rows each
    const int l15 = lane & 15, lg = (lane >> 4) & 3;
    const int row0 = blockIdx.x * 64;

    const float* Xg[3] = {send, recv, eattr};

    f32x4 acc[8];
#pragma unroll
    for (int n = 0; n < 8; ++n) acc[n] = (f32x4){0.f, 0.f, 0.f, 0.f};

    float4 ra[4][2];   // in-flight A chunks (32 VGPR): 64 rows x 16 granules / 256 thr

    auto issueA = [&](int g) {
        const float* X = Xg[g];
#pragma unroll
        for (int q = 0; q < 4; ++q) {
            int idx = tid + 256 * q;                 // 0..1023
            int row = idx >> 4, gcol = (idx & 15) * 8;
            int ge = min(row0 + row, E_EDGES - 1);
            const float* p = X + (size_t)ge * 128 + gcol;
            ra[q][0] = *(const float4*)p;
            ra[q][1] = *(const float4*)(p + 4);
        }
    };

    auto commitA = [&]() {
#pragma unroll
        for (int q = 0; q < 4; ++q) {
            int idx = tid + 256 * q;
            *(s16x8*)&ldsA[idx >> 4][(idx & 15) * 8] = cvt8(ra[q][0], ra[q][1]);
        }
    };

    auto mfma_g = [&](int g) {
        const u16* Bg = WT + g * 16384;
#pragma unroll
        for (int kk = 0; kk < 4; ++kk) {
            int k0 = kk * 32 + lg * 8;
            s16x8 a = *(const s16x8*)&ldsA[wv * 16 + l15][k0];
#pragma unroll
            for (int n = 0; n < 8; ++n) {
                s16x8 b = *(const s16x8*)(Bg + (n * 16 + l15) * 128 + k0);
                acc[n] = __builtin_amdgcn_mfma_f32_16x16x32_bf16(a, b, acc[n], 0, 0, 0);
            }
        }
    };

    issueA(0);
#pragma unroll
    for (int g = 0; g < 3; ++g) {
        if (g) { mfma_g(g - 1); SCHED0(); }   // compute g-1 while A(g) streams in
        BAR();                                 // all waves done reading ldsA(g-1)
        commitA();                             // vmcnt wait (compiler) + cvt + ds_write
        if (g < 2) issueA(g + 1);              // queue next phase's A before next drain
        SCHED0();
        WAITLGKM0();                           // ds_writes drained
        BAR();
    }
    mfma_g(2);

    float av[8];
#pragma unroll
    for (int n = 0; n < 8; ++n) av[n] = attn[n * 16 + l15];

    // reduce z per head; park in wave-private LDS; store coalesced
#pragma unroll
    for (int h = 0; h < 4; ++h) {
        float part[4];
#pragma unroll
        for (int j = 0; j < 4; ++j)
            part[j] = lrelu(acc[2 * h][j]) * av[2 * h] +
                      lrelu(acc[2 * h + 1][j]) * av[2 * h + 1];
#pragma unroll
        for (int off = 1; off < 16; off <<= 1) {
#pragma unroll
            for (int j = 0; j < 4; ++j) part[j] += __shfl_xor(part[j], off, 64);
        }
        if (l15 == h) {
#pragma unroll
            for (int j = 0; j < 4; ++j)
                smEz[wv][lg * 4 + j][h] = __expf(part[j]);
        }
    }
    // lanes 0..15: one float4 store per row (256 B contiguous per wave)
    if (lane < 16) {
        int r = row0 + wv * 16 + lane;
        if (r < E_EDGES) {
            float4 e = *(const float4*)&smEz[wv][lane][0];
            *(float4*)(ez + (size_t)r * 4) = e;
            int s = sidx[r];
            atomicAdd(&denom[(size_t)s * 4 + 0], e.x);
            atomicAdd(&denom[(size_t)s * 4 + 1], e.y);
            atomicAdd(&denom[(size_t)s * 4 + 2], e.z);
            atomicAdd(&denom[(size_t)s * 4 + 3], e.w);
        }
    }
}

// ---- K2: R11 proven structure (ldsA+ldsB, one sync), a = ez/denom fused ----
__global__ __launch_bounds__(256, 2) void k2(
    const float* __restrict__ recv, const int* __restrict__ ridx,
    const int* __restrict__ sidx, const u16* __restrict__ WTt,
    const float* __restrict__ ez, const float* __restrict__ denom,
    float* __restrict__ out0, float* __restrict__ out1)
{
    __shared__ u16 ldsA[128][136];
    __shared__ u16 ldsB[128][136];
    int tid = threadIdx.x;
    int lane = tid & 63, wv = tid >> 6;
    int l15 = lane & 15, lg = lane >> 4;
    int blockRow = blockIdx.x * 128;

    f32x4 acc[2][8];
#pragma unroll
    for (int m = 0; m < 2; ++m)
#pragma unroll
        for (int n = 0; n < 8; ++n) acc[m][n] = (f32x4){0.f, 0.f, 0.f, 0.f};

#pragma unroll
    for (int it = 0; it < 8; ++it) {
        int chunk = it * 256 + tid;
        int row = chunk >> 4, kc = (chunk & 15) << 3;
        int ge = min(blockRow + row, E_EDGES - 1);
        const float* p = recv + (size_t)ge * 128 + kc;
        float4 v0 = *(const float4*)p;
        float4 v1 = *(const float4*)(p + 4);
        *(s16x8*)&ldsA[row][kc] = cvt8(v0, v1);
    }
#pragma unroll
    for (int it = 0; it < 8; ++it) {
        int chunk = it * 256 + tid;
        int n = chunk >> 4, kc = (chunk & 15) << 3;
        *(s16x8*)&ldsB[n][kc] = *(const s16x8*)(WTt + n * 128 + kc);
    }
    __syncthreads();

#pragma unroll
    for (int kk = 0; kk < 4; ++kk) {
        int k0 = kk * 32 + lg * 8;
        s16x8 a0 = *(const s16x8*)&ldsA[wv * 32 + l15][k0];
        s16x8 a1 = *(const s16x8*)&ldsA[wv * 32 + 16 + l15][k0];
#pragma unroll
        for (int n = 0; n < 8; ++n) {
            s16x8 b = *(const s16x8*)&ldsB[n * 16 + l15][k0];
            acc[0][n] = __builtin_amdgcn_mfma_f32_16x16x32_bf16(a0, b, acc[0][n], 0, 0, 0);
            acc[1][n] = __builtin_amdgcn_mfma_f32_16x16x32_bf16(a1, b, acc[1][n], 0, 0, 0);
        }
    }

#pragma unroll
    for (int m = 0; m < 2; ++m) {
#pragma unroll
        for (int j = 0; j < 4; ++j) {
            int r = blockRow + wv * 32 + m * 16 + lg * 4 + j;
            if (r < E_EDGES) {
                int s = sidx[r];
                float4 ezv = *(const float4*)(ez + (size_t)r * 4);
                float4 dn = *(const float4*)(denom + (size_t)s * 4);
                float a0 = ezv.x / dn.x, a1 = ezv.y / dn.y;
                float a2 = ezv.z / dn.z, a3 = ezv.w / dn.w;
                float lo = 0.25f * (acc[m][0][j] * a0 + acc[m][2][j] * a1 +
                                    acc[m][4][j] * a2 + acc[m][6][j] * a3);
                float hi = 0.25f * (acc[m][1][j] * a0 + acc[m][3][j] * a1 +
                                    acc[m][5][j] * a2 + acc[m][7][j] * a3);
                out1[(size_t)r * 32 + l15] = lo;
                out1[(size_t)r * 32 + 16 + l15] = hi;
                int rv = ridx[r];
                atomicAdd(&out0[(size_t)rv * 32 + l15], lo);
                atomicAdd(&out0[(size_t)rv * 32 + 16 + l15], hi);
            }
        }
    }
}

extern "C" void kernel_launch(void* const* d_in, const int* in_sizes, int n_in,
                              void* d_out, int out_size, void* d_ws, size_t ws_size,
                              hipStream_t stream) {
    const float* recv  = (const float*)d_in[0];
    const float* send  = (const float*)d_in[1];
    const float* eattr = (const float*)d_in[2];
    const int*   sidx  = (const int*)d_in[3];
    const int*   ridx  = (const int*)d_in[4];
    const float* Wsrc  = (const float*)d_in[5];
    const float* Wtgt  = (const float*)d_in[6];
    const float* Wedge = (const float*)d_in[7];
    const float* attn  = (const float*)d_in[8];

    char* ws = (char*)d_ws;
    u16*   WT    = (u16*)ws;                         // 98304 B
    float* ez    = (float*)(ws + 131072);            // 8,000,000 B
    float* denom = (float*)(ws + 131072 + 8000000);  // 800,000 B

    float* out0 = (float*)d_out;                     // [N,32]
    float* out1 = out0 + (size_t)NN * 32;            // [E,32]

    hipMemsetAsync(denom, 0, (size_t)NN * 4 * sizeof(float), stream);
    hipMemsetAsync(out0, 0, (size_t)NN * 32 * sizeof(float), stream);

    kprep<<<192, 256, 0, stream>>>(Wsrc, Wtgt, Wedge, WT);

    int nb1 = (E_EDGES + 63) / 64;    // 7813
    int nb2 = (E_EDGES + 127) / 128;  // 3907
    k1<<<nb1, 256, 0, stream>>>(recv, send, eattr, sidx, WT, attn, ez, denom);
    k2<<<nb2, 256, 0, stream>>>(recv, ridx, sidx, WT + 16384, ez, denom, out0, out1);
}

// Round 13
// 322.470 us; speedup vs baseline: 1.7508x; 1.7508x over previous
//
#include <hip/hip_runtime.h>
#include <hip/hip_bf16.h>

#define E_EDGES 500000
#define NN 50000

typedef unsigned short u16;
typedef __attribute__((ext_vector_type(8))) short s16x8;
typedef __attribute__((ext_vector_type(4))) float f32x4;

#define BAR() __builtin_amdgcn_s_barrier()
#define SCHED0() __builtin_amdgcn_sched_barrier(0)
#define WAITLGKM0() asm volatile("s_waitcnt lgkmcnt(0)" ::: "memory")

__device__ __forceinline__ short f2bf(float f) {
    unsigned u = __builtin_bit_cast(unsigned, f);
    u += 0x7fffu + ((u >> 16) & 1u);
    return (short)(u >> 16);
}

__device__ __forceinline__ float lrelu(float x) { return x > 0.0f ? x : 0.01f * x; }

// packed fp32x8 -> bf16x8 via v_cvt_pk_bf16_f32
__device__ __forceinline__ s16x8 cvt8(float4 lo, float4 hi) {
    union { s16x8 v; __hip_bfloat162 h[4]; } u;
    u.h[0] = __float22bfloat162_rn(make_float2(lo.x, lo.y));
    u.h[1] = __float22bfloat162_rn(make_float2(lo.z, lo.w));
    u.h[2] = __float22bfloat162_rn(make_float2(hi.x, hi.y));
    u.h[3] = __float22bfloat162_rn(make_float2(hi.z, hi.w));
    return u.v;
}

// ---- weight prep: WT[g][n][k] = bf16(W_g[k][n]), g in {src, tgt, edge} ----
__global__ void kprep(const float* __restrict__ Wsrc, const float* __restrict__ Wtgt,
                      const float* __restrict__ Wedge, u16* __restrict__ WT) {
    int i = blockIdx.x * 256 + threadIdx.x;
    if (i >= 3 * 16384) return;
    int g = i >> 14, nk = i & 16383, n = nk >> 7, k = nk & 127;
    const float* W = (g == 0) ? Wsrc : (g == 1) ? Wtgt : Wedge;
    WT[i] = (u16)f2bf(W[k * 128 + n]);
}

// ---- K1: PERSISTENT version of the R11 champion. 512 blocks (2/CU), each
// loops over 7-8 contiguous 128-row tiles; R11 phase pipeline + coalesced
// epilogue verbatim inside. Phase order {send, eattr, recv} so recv is
// L3-fresh for k2. Single-buffer ra (static indices). ----
__global__ __launch_bounds__(256, 2) void k1(
    const float* __restrict__ recv, const float* __restrict__ send,
    const float* __restrict__ eattr, const int* __restrict__ sidx,
    const u16* __restrict__ WT, const float* __restrict__ attn,
    float* __restrict__ ez, float* __restrict__ denom)
{
    __shared__ u16 ldsA[128][136];
    __shared__ u16 ldsB[128][136];
    __shared__ float smEz[4][32][4];   // wave-private
    const int tid = threadIdx.x;
    const int lane = tid & 63, wv = tid >> 6;
    const int l15 = lane & 15, lg = (lane >> 4) & 3;

    const int b = blockIdx.x;
    const int start = b * 7 + min(b, 323);          // 3907 tiles over 512 blocks
    const int end = start + 7 + (b < 323 ? 1 : 0);

    // stream order: send, eattr, recv  (q-sum is commutative; recv last => L3-warm for k2)
    const float* Xg[3] = {send, eattr, recv};
    const int bgoff[3] = {0, 2 * 16384, 1 * 16384}; // Wsrc, Wedge, Wtgt

    float av[8];
#pragma unroll
    for (int n = 0; n < 8; ++n) av[n] = attn[n * 16 + l15];

    f32x4 acc[2][8];
    float4 ra[8][2];

    auto issueA = [&](const float* X, int tileRow) {
#pragma unroll
        for (int q = 0; q < 8; ++q) {
            int idx = tid + 256 * q;
            int row = idx >> 4, gcol = (idx & 15) * 8;
            int ge = min(tileRow + row, E_EDGES - 1);
            const float* p = X + (size_t)ge * 128 + gcol;
            ra[q][0] = *(const float4*)p;
            ra[q][1] = *(const float4*)(p + 4);
        }
    };

    auto commitA = [&]() {
#pragma unroll
        for (int q = 0; q < 8; ++q) {
            int idx = tid + 256 * q;
            *(s16x8*)&ldsA[idx >> 4][(idx & 15) * 8] = cvt8(ra[q][0], ra[q][1]);
        }
    };

    auto mfma_g = [&]() {
#pragma unroll
        for (int kk = 0; kk < 4; ++kk) {
            int k0 = kk * 32 + lg * 8;
            s16x8 a0 = *(const s16x8*)&ldsA[wv * 32 + l15][k0];
            s16x8 a1 = *(const s16x8*)&ldsA[wv * 32 + 16 + l15][k0];
#pragma unroll
            for (int n = 0; n < 8; ++n) {
                s16x8 bfr = *(const s16x8*)&ldsB[n * 16 + l15][k0];
                acc[0][n] = __builtin_amdgcn_mfma_f32_16x16x32_bf16(a0, bfr, acc[0][n], 0, 0, 0);
                acc[1][n] = __builtin_amdgcn_mfma_f32_16x16x32_bf16(a1, bfr, acc[1][n], 0, 0, 0);
            }
        }
    };

    issueA(Xg[0], start * 128);

    for (int t = start; t < end; ++t) {
        const int row0 = t * 128;
#pragma unroll
        for (int m = 0; m < 2; ++m)
#pragma unroll
            for (int n = 0; n < 8; ++n) acc[m][n] = (f32x4){0.f, 0.f, 0.f, 0.f};

#pragma unroll
        for (int g = 0; g < 3; ++g) {
            BAR();                               // all waves done reading prev LDS
            s16x8 rb[8];
            {
                const u16* Bg = WT + bgoff[g];
#pragma unroll
                for (int q = 0; q < 8; ++q) {
                    int idx = tid + 256 * q;
                    rb[q] = *(const s16x8*)(Bg + (idx >> 4) * 128 + (idx & 15) * 8);
                }
            }
            commitA();                           // drains this phase's A
            if (g < 2) issueA(Xg[g + 1], row0);  // queue next stream
            else if (t + 1 < end) issueA(Xg[0], row0 + 128);
            SCHED0();
#pragma unroll
            for (int q = 0; q < 8; ++q) {
                int idx = tid + 256 * q;
                *(s16x8*)&ldsB[idx >> 4][(idx & 15) * 8] = rb[q];
            }
            SCHED0();
            WAITLGKM0();
            BAR();
            mfma_g();                            // next-phase loads fly during MFMA
        }

        // epilogue (R11): butterfly reduce z, park in wave-private LDS, coalesced store
#pragma unroll
        for (int m = 0; m < 2; ++m) {
#pragma unroll
            for (int h = 0; h < 4; ++h) {
                float part[4];
#pragma unroll
                for (int j = 0; j < 4; ++j)
                    part[j] = lrelu(acc[m][2 * h][j]) * av[2 * h] +
                              lrelu(acc[m][2 * h + 1][j]) * av[2 * h + 1];
#pragma unroll
                for (int off = 1; off < 16; off <<= 1) {
#pragma unroll
                    for (int j = 0; j < 4; ++j) part[j] += __shfl_xor(part[j], off, 64);
                }
                if (l15 == h) {
#pragma unroll
                    for (int j = 0; j < 4; ++j)
                        smEz[wv][m * 16 + lg * 4 + j][h] = __expf(part[j]);
                }
            }
        }
        {
            int row = lane >> 1, hp = (lane & 1) * 2;
            int r = row0 + wv * 32 + row;
            float e0 = smEz[wv][row][hp];
            float e1 = smEz[wv][row][hp + 1];
            if (r < E_EDGES) {
                *(float2*)(ez + (size_t)r * 4 + hp) = make_float2(e0, e1);
                int s = sidx[r];
                atomicAdd(&denom[(size_t)s * 4 + hp], e0);
                atomicAdd(&denom[(size_t)s * 4 + hp + 1], e1);
            }
        }
    }
}

// ---- K2: R11 proven structure (ldsA+ldsB, one sync), a = ez/denom fused ----
__global__ __launch_bounds__(256, 2) void k2(
    const float* __restrict__ recv, const int* __restrict__ ridx,
    const int* __restrict__ sidx, const u16* __restrict__ WTt,
    const float* __restrict__ ez, const float* __restrict__ denom,
    float* __restrict__ out0, float* __restrict__ out1)
{
    __shared__ u16 ldsA[128][136];
    __shared__ u16 ldsB[128][136];
    int tid = threadIdx.x;
    int lane = tid & 63, wv = tid >> 6;
    int l15 = lane & 15, lg = lane >> 4;
    int blockRow = blockIdx.x * 128;

    f32x4 acc[2][8];
#pragma unroll
    for (int m = 0; m < 2; ++m)
#pragma unroll
        for (int n = 0; n < 8; ++n) acc[m][n] = (f32x4){0.f, 0.f, 0.f, 0.f};

#pragma unroll
    for (int it = 0; it < 8; ++it) {
        int chunk = it * 256 + tid;
        int row = chunk >> 4, kc = (chunk & 15) << 3;
        int ge = min(blockRow + row, E_EDGES - 1);
        const float* p = recv + (size_t)ge * 128 + kc;
        float4 v0 = *(const float4*)p;
        float4 v1 = *(const float4*)(p + 4);
        *(s16x8*)&ldsA[row][kc] = cvt8(v0, v1);
    }
#pragma unroll
    for (int it = 0; it < 8; ++it) {
        int chunk = it * 256 + tid;
        int n = chunk >> 4, kc = (chunk & 15) << 3;
        *(s16x8*)&ldsB[n][kc] = *(const s16x8*)(WTt + n * 128 + kc);
    }
    __syncthreads();

#pragma unroll
    for (int kk = 0; kk < 4; ++kk) {
        int k0 = kk * 32 + lg * 8;
        s16x8 a0 = *(const s16x8*)&ldsA[wv * 32 + l15][k0];
        s16x8 a1 = *(const s16x8*)&ldsA[wv * 32 + 16 + l15][k0];
#pragma unroll
        for (int n = 0; n < 8; ++n) {
            s16x8 b = *(const s16x8*)&ldsB[n * 16 + l15][k0];
            acc[0][n] = __builtin_amdgcn_mfma_f32_16x16x32_bf16(a0, b, acc[0][n], 0, 0, 0);
            acc[1][n] = __builtin_amdgcn_mfma_f32_16x16x32_bf16(a1, b, acc[1][n], 0, 0, 0);
        }
    }

#pragma unroll
    for (int m = 0; m < 2; ++m) {
#pragma unroll
        for (int j = 0; j < 4; ++j) {
            int r = blockRow + wv * 32 + m * 16 + lg * 4 + j;
            if (r < E_EDGES) {
                int s = sidx[r];
                float4 ezv = *(const float4*)(ez + (size_t)r * 4);
                float4 dn = *(const float4*)(denom + (size_t)s * 4);
                float a0 = ezv.x / dn.x, a1 = ezv.y / dn.y;
                float a2 = ezv.z / dn.z, a3 = ezv.w / dn.w;
                float lo = 0.25f * (acc[m][0][j] * a0 + acc[m][2][j] * a1 +
                                    acc[m][4][j] * a2 + acc[m][6][j] * a3);
                float hi = 0.25f * (acc[m][1][j] * a0 + acc[m][3][j] * a1 +
                                    acc[m][5][j] * a2 + acc[m][7][j] * a3);
                out1[(size_t)r * 32 + l15] = lo;
                out1[(size_t)r * 32 + 16 + l15] = hi;
                int rv = ridx[r];
                atomicAdd(&out0[(size_t)rv * 32 + l15], lo);
                atomicAdd(&out0[(size_t)rv * 32 + 16 + l15], hi);
            }
        }
    }
}

extern "C" void kernel_launch(void* const* d_in, const int* in_sizes, int n_in,
                              void* d_out, int out_size, void* d_ws, size_t ws_size,
                              hipStream_t stream) {
    const float* recv  = (const float*)d_in[0];
    const float* send  = (const float*)d_in[1];
    const float* eattr = (const float*)d_in[2];
    const int*   sidx  = (const int*)d_in[3];
    const int*   ridx  = (const int*)d_in[4];
    const float* Wsrc  = (const float*)d_in[5];
    const float* Wtgt  = (const float*)d_in[6];
    const float* Wedge = (const float*)d_in[7];
    const float* attn  = (const float*)d_in[8];

    char* ws = (char*)d_ws;
    u16*   WT    = (u16*)ws;                         // 98304 B
    float* ez    = (float*)(ws + 131072);            // 8,000,000 B
    float* denom = (float*)(ws + 131072 + 8000000);  // 800,000 B

    float* out0 = (float*)d_out;                     // [N,32]
    float* out1 = out0 + (size_t)NN * 32;            // [E,32]

    hipMemsetAsync(denom, 0, (size_t)NN * 4 * sizeof(float), stream);
    hipMemsetAsync(out0, 0, (size_t)NN * 32 * sizeof(float), stream);

    kprep<<<192, 256, 0, stream>>>(Wsrc, Wtgt, Wedge, WT);

    k1<<<512, 256, 0, stream>>>(recv, send, eattr, sidx, WT, attn, ez, denom);
    int nb2 = (E_EDGES + 127) / 128;  // 3907
    k2<<<nb2, 256, 0, stream>>>(recv, ridx, sidx, WT + 16384, ez, denom, out0, out1);
}

// Round 14
// 305.373 us; speedup vs baseline: 1.8488x; 1.0560x over previous
//
#include <hip/hip_runtime.h>
#include <hip/hip_bf16.h>

#define E_EDGES 500000
#define NN 50000

typedef unsigned short u16;
typedef __attribute__((ext_vector_type(8))) short s16x8;
typedef __attribute__((ext_vector_type(4))) float f32x4;

#define BAR() __builtin_amdgcn_s_barrier()
#define SCHED0() __builtin_amdgcn_sched_barrier(0)
#define WAITLGKM0() asm volatile("s_waitcnt lgkmcnt(0)" ::: "memory")

__device__ __forceinline__ short f2bf(float f) {
    unsigned u = __builtin_bit_cast(unsigned, f);
    u += 0x7fffu + ((u >> 16) & 1u);
    return (short)(u >> 16);
}

__device__ __forceinline__ float lrelu(float x) { return x > 0.0f ? x : 0.01f * x; }

// packed fp32x8 -> bf16x8 via v_cvt_pk_bf16_f32
__device__ __forceinline__ s16x8 cvt8(float4 lo, float4 hi) {
    union { s16x8 v; __hip_bfloat162 h[4]; } u;
    u.h[0] = __float22bfloat162_rn(make_float2(lo.x, lo.y));
    u.h[1] = __float22bfloat162_rn(make_float2(lo.z, lo.w));
    u.h[2] = __float22bfloat162_rn(make_float2(hi.x, hi.y));
    u.h[3] = __float22bfloat162_rn(make_float2(hi.z, hi.w));
    return u.v;
}

// ---- weight prep: WT[g][n][k] = bf16(W_g[k][n]), g in {src, tgt, edge} ----
__global__ void kprep(const float* __restrict__ Wsrc, const float* __restrict__ Wtgt,
                      const float* __restrict__ Wedge, u16* __restrict__ WT) {
    int i = blockIdx.x * 256 + threadIdx.x;
    if (i >= 3 * 16384) return;
    int g = i >> 14, nk = i & 16383, n = nk >> 7, k = nk & 127;
    const float* W = (g == 0) ? Wsrc : (g == 1) ? Wtgt : Wedge;
    WT[i] = (u16)f2bf(W[k * 128 + n]);
}

// ---- K1: R11 champion body verbatim; ONLY change = phase stream order
// {send, eattr, recv} so recv is L3-fresh when k2 launches. ----
__global__ __launch_bounds__(256, 2) void k1(
    const float* __restrict__ recv, const float* __restrict__ send,
    const float* __restrict__ eattr, const int* __restrict__ sidx,
    const u16* __restrict__ WT, const float* __restrict__ attn,
    float* __restrict__ ez, float* __restrict__ denom)
{
    __shared__ u16 ldsA[128][136];
    __shared__ u16 ldsB[128][136];
    __shared__ float smEz[4][32][4];   // 2 KB, wave-private regions
    const int tid = threadIdx.x;
    const int lane = tid & 63, wv = tid >> 6;
    const int l15 = lane & 15, lg = (lane >> 4) & 3;
    const int blockRow = blockIdx.x * 128;

    // stream order: send, eattr, recv (q-sum commutative; recv last => L3-warm for k2)
    const float* Xg[3] = {send, eattr, recv};
    const int bgoff[3] = {0, 2 * 16384, 1 * 16384};  // Wsrc, Wedge, Wtgt

    f32x4 acc[2][8];
#pragma unroll
    for (int m = 0; m < 2; ++m)
#pragma unroll
        for (int n = 0; n < 8; ++n) acc[m][n] = (f32x4){0.f, 0.f, 0.f, 0.f};

    float4 ra[2][8][2];   // double-buffered in-flight A (128 VGPR)

    auto issueA = [&](int g, int buf) {
        const float* X = Xg[g];
#pragma unroll
        for (int q = 0; q < 8; ++q) {
            int idx = tid + 256 * q;
            int row = idx >> 4, gcol = (idx & 15) * 8;
            int ge = min(blockRow + row, E_EDGES - 1);
            const float* p = X + (size_t)ge * 128 + gcol;
            ra[buf][q][0] = *(const float4*)p;
            ra[buf][q][1] = *(const float4*)(p + 4);
        }
    };

    auto commitA = [&](int buf) {
#pragma unroll
        for (int q = 0; q < 8; ++q) {
            int idx = tid + 256 * q;
            *(s16x8*)&ldsA[idx >> 4][(idx & 15) * 8] = cvt8(ra[buf][q][0], ra[buf][q][1]);
        }
    };

    auto mfma_g = [&]() {
#pragma unroll
        for (int kk = 0; kk < 4; ++kk) {
            int k0 = kk * 32 + lg * 8;
            s16x8 a0 = *(const s16x8*)&ldsA[wv * 32 + l15][k0];
            s16x8 a1 = *(const s16x8*)&ldsA[wv * 32 + 16 + l15][k0];
#pragma unroll
            for (int n = 0; n < 8; ++n) {
                s16x8 b = *(const s16x8*)&ldsB[n * 16 + l15][k0];
                acc[0][n] = __builtin_amdgcn_mfma_f32_16x16x32_bf16(a0, b, acc[0][n], 0, 0, 0);
                acc[1][n] = __builtin_amdgcn_mfma_f32_16x16x32_bf16(a1, b, acc[1][n], 0, 0, 0);
            }
        }
    };

    issueA(0, 0);
#pragma unroll
    for (int g = 0; g < 3; ++g) {
        if (g) { mfma_g(); SCHED0(); }      // compute g-1 while A(g) streams in
        BAR();                               // all waves done reading LDS(g-1)
        s16x8 rb[8];
        {
            const u16* Bg = WT + bgoff[g];
#pragma unroll
            for (int q = 0; q < 8; ++q) {
                int idx = tid + 256 * q;
                rb[q] = *(const s16x8*)(Bg + (idx >> 4) * 128 + (idx & 15) * 8);
            }
        }
        if (g < 2) issueA(g + 1, (g + 1) & 1);  // queue next-phase A before drain
        SCHED0();
        commitA(g & 1);
#pragma unroll
        for (int q = 0; q < 8; ++q) {
            int idx = tid + 256 * q;
            *(s16x8*)&ldsB[idx >> 4][(idx & 15) * 8] = rb[q];
        }
        SCHED0();
        WAITLGKM0();
        BAR();
    }
    mfma_g();                                // g = 2

    float av[8];
#pragma unroll
    for (int n = 0; n < 8; ++n) av[n] = attn[n * 16 + l15];

    // butterfly leaves the sum in ALL 16 lanes of each lg-group; park results
    // in wave-private LDS, then store coalesced.
#pragma unroll
    for (int m = 0; m < 2; ++m) {
#pragma unroll
        for (int h = 0; h < 4; ++h) {
            float part[4];
#pragma unroll
            for (int j = 0; j < 4; ++j)
                part[j] = lrelu(acc[m][2 * h][j]) * av[2 * h] +
                          lrelu(acc[m][2 * h + 1][j]) * av[2 * h + 1];
#pragma unroll
            for (int off = 1; off < 16; off <<= 1) {
#pragma unroll
                for (int j = 0; j < 4; ++j) part[j] += __shfl_xor(part[j], off, 64);
            }
            if (l15 == h) {
#pragma unroll
                for (int j = 0; j < 4; ++j)
                    smEz[wv][m * 16 + lg * 4 + j][h] = __expf(part[j]);
            }
        }
    }
    // wave-private region: in-order LDS per wave, compiler inserts lgkm wait
    {
        int row = lane >> 1, hp = (lane & 1) * 2;
        int r = blockRow + wv * 32 + row;
        float e0 = smEz[wv][row][hp];
        float e1 = smEz[wv][row][hp + 1];
        if (r < E_EDGES) {
            *(float2*)(ez + (size_t)r * 4 + hp) = make_float2(e0, e1);
            int s = sidx[r];
            atomicAdd(&denom[(size_t)s * 4 + hp], e0);
            atomicAdd(&denom[(size_t)s * 4 + hp + 1], e1);
        }
    }
}

// ---- K2: R11 proven structure (ldsA+ldsB, one sync), a = ez/denom fused ----
__global__ __launch_bounds__(256, 2) void k2(
    const float* __restrict__ recv, const int* __restrict__ ridx,
    const int* __restrict__ sidx, const u16* __restrict__ WTt,
    const float* __restrict__ ez, const float* __restrict__ denom,
    float* __restrict__ out0, float* __restrict__ out1)
{
    __shared__ u16 ldsA[128][136];
    __shared__ u16 ldsB[128][136];
    int tid = threadIdx.x;
    int lane = tid & 63, wv = tid >> 6;
    int l15 = lane & 15, lg = lane >> 4;
    int blockRow = blockIdx.x * 128;

    f32x4 acc[2][8];
#pragma unroll
    for (int m = 0; m < 2; ++m)
#pragma unroll
        for (int n = 0; n < 8; ++n) acc[m][n] = (f32x4){0.f, 0.f, 0.f, 0.f};

#pragma unroll
    for (int it = 0; it < 8; ++it) {
        int chunk = it * 256 + tid;
        int row = chunk >> 4, kc = (chunk & 15) << 3;
        int ge = min(blockRow + row, E_EDGES - 1);
        const float* p = recv + (size_t)ge * 128 + kc;
        float4 v0 = *(const float4*)p;
        float4 v1 = *(const float4*)(p + 4);
        *(s16x8*)&ldsA[row][kc] = cvt8(v0, v1);
    }
#pragma unroll
    for (int it = 0; it < 8; ++it) {
        int chunk = it * 256 + tid;
        int n = chunk >> 4, kc = (chunk & 15) << 3;
        *(s16x8*)&ldsB[n][kc] = *(const s16x8*)(WTt + n * 128 + kc);
    }
    __syncthreads();

#pragma unroll
    for (int kk = 0; kk < 4; ++kk) {
        int k0 = kk * 32 + lg * 8;
        s16x8 a0 = *(const s16x8*)&ldsA[wv * 32 + l15][k0];
        s16x8 a1 = *(const s16x8*)&ldsA[wv * 32 + 16 + l15][k0];
#pragma unroll
        for (int n = 0; n < 8; ++n) {
            s16x8 b = *(const s16x8*)&ldsB[n * 16 + l15][k0];
            acc[0][n] = __builtin_amdgcn_mfma_f32_16x16x32_bf16(a0, b, acc[0][n], 0, 0, 0);
            acc[1][n] = __builtin_amdgcn_mfma_f32_16x16x32_bf16(a1, b, acc[1][n], 0, 0, 0);
        }
    }

#pragma unroll
    for (int m = 0; m < 2; ++m) {
#pragma unroll
        for (int j = 0; j < 4; ++j) {
            int r = blockRow + wv * 32 + m * 16 + lg * 4 + j;
            if (r < E_EDGES) {
                int s = sidx[r];
                float4 ezv = *(const float4*)(ez + (size_t)r * 4);
                float4 dn = *(const float4*)(denom + (size_t)s * 4);
                float a0 = ezv.x / dn.x, a1 = ezv.y / dn.y;
                float a2 = ezv.z / dn.z, a3 = ezv.w / dn.w;
                float lo = 0.25f * (acc[m][0][j] * a0 + acc[m][2][j] * a1 +
                                    acc[m][4][j] * a2 + acc[m][6][j] * a3);
                float hi = 0.25f * (acc[m][1][j] * a0 + acc[m][3][j] * a1 +
                                    acc[m][5][j] * a2 + acc[m][7][j] * a3);
                out1[(size_t)r * 32 + l15] = lo;
                out1[(size_t)r * 32 + 16 + l15] = hi;
                int rv = ridx[r];
                atomicAdd(&out0[(size_t)rv * 32 + l15], lo);
                atomicAdd(&out0[(size_t)rv * 32 + 16 + l15], hi);
            }
        }
    }
}

extern "C" void kernel_launch(void* const* d_in, const int* in_sizes, int n_in,
                              void* d_out, int out_size, void* d_ws, size_t ws_size,
                              hipStream_t stream) {
    const float* recv  = (const float*)d_in[0];
    const float* send  = (const float*)d_in[1];
    const float* eattr = (const float*)d_in[2];
    const int*   sidx  = (const int*)d_in[3];
    const int*   ridx  = (const int*)d_in[4];
    const float* Wsrc  = (const float*)d_in[5];
    const float* Wtgt  = (const float*)d_in[6];
    const float* Wedge = (const float*)d_in[7];
    const float* attn  = (const float*)d_in[8];

    char* ws = (char*)d_ws;
    u16*   WT    = (u16*)ws;                         // 98304 B
    float* ez    = (float*)(ws + 131072);            // 8,000,000 B
    float* denom = (float*)(ws + 131072 + 8000000);  // 800,000 B

    float* out0 = (float*)d_out;                     // [N,32]
    float* out1 = out0 + (size_t)NN * 32;            // [E,32]

    hipMemsetAsync(denom, 0, (size_t)NN * 4 * sizeof(float), stream);
    hipMemsetAsync(out0, 0, (size_t)NN * 32 * sizeof(float), stream);

    kprep<<<192, 256, 0, stream>>>(Wsrc, Wtgt, Wedge, WT);

    int nb = (E_EDGES + 127) / 128;  // 3907
    k1<<<nb, 256, 0, stream>>>(recv, send, eattr, sidx, WT, attn, ez, denom);
    k2<<<nb, 256, 0, stream>>>(recv, ridx, sidx, WT + 16384, ez, denom, out0, out1);
}

// Round 15
// 300.616 us; speedup vs baseline: 1.8780x; 1.0158x over previous
//
#include <hip/hip_runtime.h>
#include <hip/hip_bf16.h>

#define E_EDGES 500000
#define NN 50000

typedef unsigned short u16;
typedef __attribute__((ext_vector_type(8))) short s16x8;
typedef __attribute__((ext_vector_type(4))) float f32x4;

#define BAR() __builtin_amdgcn_s_barrier()
#define SCHED0() __builtin_amdgcn_sched_barrier(0)
#define WAITLGKM0() asm volatile("s_waitcnt lgkmcnt(0)" ::: "memory")

__device__ __forceinline__ short f2bf(float f) {
    unsigned u = __builtin_bit_cast(unsigned, f);
    u += 0x7fffu + ((u >> 16) & 1u);
    return (short)(u >> 16);
}

__device__ __forceinline__ float lrelu(float x) { return x > 0.0f ? x : 0.01f * x; }

// packed fp32x8 -> bf16x8 via v_cvt_pk_bf16_f32
__device__ __forceinline__ s16x8 cvt8(float4 lo, float4 hi) {
    union { s16x8 v; __hip_bfloat162 h[4]; } u;
    u.h[0] = __float22bfloat162_rn(make_float2(lo.x, lo.y));
    u.h[1] = __float22bfloat162_rn(make_float2(lo.z, lo.w));
    u.h[2] = __float22bfloat162_rn(make_float2(hi.x, hi.y));
    u.h[3] = __float22bfloat162_rn(make_float2(hi.z, hi.w));
    return u.v;
}

// ---- weight prep: WT[g][n][k] = bf16(W_g[k][n]), g in {src, tgt, edge} ----
__global__ void kprep(const float* __restrict__ Wsrc, const float* __restrict__ Wtgt,
                      const float* __restrict__ Wedge, u16* __restrict__ WT) {
    int i = blockIdx.x * 256 + threadIdx.x;
    if (i >= 3 * 16384) return;
    int g = i >> 14, nk = i & 16383, n = nk >> 7, k = nk & 127;
    const float* W = (g == 0) ? Wsrc : (g == 1) ? Wtgt : Wedge;
    WT[i] = (u16)f2bf(W[k * 128 + n]);
}

// ---- K1: champion phase-overlap skeleton at M=64.
// LDS = ldsA 17.4K + ldsB 34.8K + smEz 1K = 53.2 KB -> 3 blocks/CU.
// acc 32 + ra 32 + rb 32 VGPR -> fits the 128-reg sweet spot. ----
__global__ __launch_bounds__(256, 2) void k1(
    const float* __restrict__ recv, const float* __restrict__ send,
    const float* __restrict__ eattr, const int* __restrict__ sidx,
    const u16* __restrict__ WT, const float* __restrict__ attn,
    float* __restrict__ ez, float* __restrict__ denom)
{
    __shared__ u16 ldsA[64][136];      // 17408 B
    __shared__ u16 ldsB[128][136];     // 34816 B
    __shared__ float smEz[4][16][4];   // 1 KB, wave-private
    const int tid = threadIdx.x;
    const int lane = tid & 63, wv = tid >> 6;        // 4 waves, 16 rows each
    const int l15 = lane & 15, lg = (lane >> 4) & 3;
    const int row0 = blockIdx.x * 64;

    const float* Xg[3] = {send, eattr, recv};
    const int bgoff[3] = {0, 2 * 16384, 1 * 16384};  // Wsrc, Wedge, Wtgt

    f32x4 acc[8];
#pragma unroll
    for (int n = 0; n < 8; ++n) acc[n] = (f32x4){0.f, 0.f, 0.f, 0.f};

    float4 ra[4][2];   // in-flight A (32 VGPR): 64 rows x 16 granules / 256 thr

    auto issueA = [&](int g) {
        const float* X = Xg[g];
#pragma unroll
        for (int q = 0; q < 4; ++q) {
            int idx = tid + 256 * q;                 // 0..1023
            int row = idx >> 4, gcol = (idx & 15) * 8;
            int ge = min(row0 + row, E_EDGES - 1);
            const float* p = X + (size_t)ge * 128 + gcol;
            ra[q][0] = *(const float4*)p;
            ra[q][1] = *(const float4*)(p + 4);
        }
    };

    auto commitA = [&]() {
#pragma unroll
        for (int q = 0; q < 4; ++q) {
            int idx = tid + 256 * q;
            *(s16x8*)&ldsA[idx >> 4][(idx & 15) * 8] = cvt8(ra[q][0], ra[q][1]);
        }
    };

    auto mfma_g = [&]() {
#pragma unroll
        for (int kk = 0; kk < 4; ++kk) {
            int k0 = kk * 32 + lg * 8;
            s16x8 a = *(const s16x8*)&ldsA[wv * 16 + l15][k0];
#pragma unroll
            for (int n = 0; n < 8; ++n) {
                s16x8 b = *(const s16x8*)&ldsB[n * 16 + l15][k0];
                acc[n] = __builtin_amdgcn_mfma_f32_16x16x32_bf16(a, b, acc[n], 0, 0, 0);
            }
        }
    };

    issueA(0);
#pragma unroll
    for (int g = 0; g < 3; ++g) {
        if (g) { mfma_g(); SCHED0(); }      // compute g-1 while nothing blocks loads
        BAR();                               // all waves done reading LDS(g-1)
        s16x8 rb[8];
        {
            const u16* Bg = WT + bgoff[g];
#pragma unroll
            for (int q = 0; q < 8; ++q) {
                int idx = tid + 256 * q;
                rb[q] = *(const s16x8*)(Bg + (idx >> 4) * 128 + (idx & 15) * 8);
            }
        }
        commitA();                           // drains this phase's A
        if (g < 2) issueA(g + 1);            // queue next stream behind the drain
        SCHED0();
#pragma unroll
        for (int q = 0; q < 8; ++q) {
            int idx = tid + 256 * q;
            *(s16x8*)&ldsB[idx >> 4][(idx & 15) * 8] = rb[q];
        }
        SCHED0();
        WAITLGKM0();
        BAR();
    }
    mfma_g();                                // g = 2

    float av[8];
#pragma unroll
    for (int n = 0; n < 8; ++n) av[n] = attn[n * 16 + l15];

    // reduce z per head; park in wave-private LDS; store fully coalesced
#pragma unroll
    for (int h = 0; h < 4; ++h) {
        float part[4];
#pragma unroll
        for (int j = 0; j < 4; ++j)
            part[j] = lrelu(acc[2 * h][j]) * av[2 * h] +
                      lrelu(acc[2 * h + 1][j]) * av[2 * h + 1];
#pragma unroll
        for (int off = 1; off < 16; off <<= 1) {
#pragma unroll
            for (int j = 0; j < 4; ++j) part[j] += __shfl_xor(part[j], off, 64);
        }
        if (l15 == h) {
#pragma unroll
            for (int j = 0; j < 4; ++j)
                smEz[wv][lg * 4 + j][h] = __expf(part[j]);
        }
    }
    // lane -> (row = lane>>2, head = lane&3): 64 lanes = 256 B contiguous ez
    {
        int row = lane >> 2, h = lane & 3;
        int r = row0 + wv * 16 + row;
        float v = smEz[wv][row][h];
        if (r < E_EDGES) {
            ez[(size_t)r * 4 + h] = v;
            int s = sidx[r];
            atomicAdd(&denom[(size_t)s * 4 + h], v);
        }
    }
}

// ---- K2: champion structure unchanged (ldsA+ldsB, one sync), a = ez/denom fused ----
__global__ __launch_bounds__(256, 2) void k2(
    const float* __restrict__ recv, const int* __restrict__ ridx,
    const int* __restrict__ sidx, const u16* __restrict__ WTt,
    const float* __restrict__ ez, const float* __restrict__ denom,
    float* __restrict__ out0, float* __restrict__ out1)
{
    __shared__ u16 ldsA[128][136];
    __shared__ u16 ldsB[128][136];
    int tid = threadIdx.x;
    int lane = tid & 63, wv = tid >> 6;
    int l15 = lane & 15, lg = lane >> 4;
    int blockRow = blockIdx.x * 128;

    f32x4 acc[2][8];
#pragma unroll
    for (int m = 0; m < 2; ++m)
#pragma unroll
        for (int n = 0; n < 8; ++n) acc[m][n] = (f32x4){0.f, 0.f, 0.f, 0.f};

#pragma unroll
    for (int it = 0; it < 8; ++it) {
        int chunk = it * 256 + tid;
        int row = chunk >> 4, kc = (chunk & 15) << 3;
        int ge = min(blockRow + row, E_EDGES - 1);
        const float* p = recv + (size_t)ge * 128 + kc;
        float4 v0 = *(const float4*)p;
        float4 v1 = *(const float4*)(p + 4);
        *(s16x8*)&ldsA[row][kc] = cvt8(v0, v1);
    }
#pragma unroll
    for (int it = 0; it < 8; ++it) {
        int chunk = it * 256 + tid;
        int n = chunk >> 4, kc = (chunk & 15) << 3;
        *(s16x8*)&ldsB[n][kc] = *(const s16x8*)(WTt + n * 128 + kc);
    }
    __syncthreads();

#pragma unroll
    for (int kk = 0; kk < 4; ++kk) {
        int k0 = kk * 32 + lg * 8;
        s16x8 a0 = *(const s16x8*)&ldsA[wv * 32 + l15][k0];
        s16x8 a1 = *(const s16x8*)&ldsA[wv * 32 + 16 + l15][k0];
#pragma unroll
        for (int n = 0; n < 8; ++n) {
            s16x8 b = *(const s16x8*)&ldsB[n * 16 + l15][k0];
            acc[0][n] = __builtin_amdgcn_mfma_f32_16x16x32_bf16(a0, b, acc[0][n], 0, 0, 0);
            acc[1][n] = __builtin_amdgcn_mfma_f32_16x16x32_bf16(a1, b, acc[1][n], 0, 0, 0);
        }
    }

#pragma unroll
    for (int m = 0; m < 2; ++m) {
#pragma unroll
        for (int j = 0; j < 4; ++j) {
            int r = blockRow + wv * 32 + m * 16 + lg * 4 + j;
            if (r < E_EDGES) {
                int s = sidx[r];
                float4 ezv = *(const float4*)(ez + (size_t)r * 4);
                float4 dn = *(const float4*)(denom + (size_t)s * 4);
                float a0 = ezv.x / dn.x, a1 = ezv.y / dn.y;
                float a2 = ezv.z / dn.z, a3 = ezv.w / dn.w;
                float lo = 0.25f * (acc[m][0][j] * a0 + acc[m][2][j] * a1 +
                                    acc[m][4][j] * a2 + acc[m][6][j] * a3);
                float hi = 0.25f * (acc[m][1][j] * a0 + acc[m][3][j] * a1 +
                                    acc[m][5][j] * a2 + acc[m][7][j] * a3);
                out1[(size_t)r * 32 + l15] = lo;
                out1[(size_t)r * 32 + 16 + l15] = hi;
                int rv = ridx[r];
                atomicAdd(&out0[(size_t)rv * 32 + l15], lo);
                atomicAdd(&out0[(size_t)rv * 32 + 16 + l15], hi);
            }
        }
    }
}

extern "C" void kernel_launch(void* const* d_in, const int* in_sizes, int n_in,
                              void* d_out, int out_size, void* d_ws, size_t ws_size,
                              hipStream_t stream) {
    const float* recv  = (const float*)d_in[0];
    const float* send  = (const float*)d_in[1];
    const float* eattr = (const float*)d_in[2];
    const int*   sidx  = (const int*)d_in[3];
    const int*   ridx  = (const int*)d_in[4];
    const float* Wsrc  = (const float*)d_in[5];
    const float* Wtgt  = (const float*)d_in[6];
    const float* Wedge = (const float*)d_in[7];
    const float* attn  = (const float*)d_in[8];

    char* ws = (char*)d_ws;
    u16*   WT    = (u16*)ws;                         // 98304 B
    float* ez    = (float*)(ws + 131072);            // 8,000,000 B
    float* denom = (float*)(ws + 131072 + 8000000);  // 800,000 B

    float* out0 = (float*)d_out;                     // [N,32]
    float* out1 = out0 + (size_t)NN * 32;            // [E,32]

    hipMemsetAsync(denom, 0, (size_t)NN * 4 * sizeof(float), stream);
    hipMemsetAsync(out0, 0, (size_t)NN * 32 * sizeof(float), stream);

    kprep<<<192, 256, 0, stream>>>(Wsrc, Wtgt, Wedge, WT);

    int nb1 = (E_EDGES + 63) / 64;    // 7813
    int nb2 = (E_EDGES + 127) / 128;  // 3907
    k1<<<nb1, 256, 0, stream>>>(recv, send, eattr, sidx, WT, attn, ez, denom);
    k2<<<nb2, 256, 0, stream>>>(recv, ridx, sidx, WT + 16384, ez, denom, out0, out1);
}

// Round 16
// 299.864 us; speedup vs baseline: 1.8827x; 1.0025x over previous
//
#include <hip/hip_runtime.h>
#include <hip/hip_bf16.h>

#define E_EDGES 500000
#define NN 50000

typedef unsigned short u16;
typedef __attribute__((ext_vector_type(8))) short s16x8;
typedef __attribute__((ext_vector_type(4))) float f32x4;

#define BAR() __builtin_amdgcn_s_barrier()
#define SCHED0() __builtin_amdgcn_sched_barrier(0)
#define WAITLGKM0() asm volatile("s_waitcnt lgkmcnt(0)" ::: "memory")

__device__ __forceinline__ short f2bf(float f) {
    unsigned u = __builtin_bit_cast(unsigned, f);
    u += 0x7fffu + ((u >> 16) & 1u);
    return (short)(u >> 16);
}

__device__ __forceinline__ float lrelu(float x) { return x > 0.0f ? x : 0.01f * x; }

// packed fp32x8 -> bf16x8 via v_cvt_pk_bf16_f32
__device__ __forceinline__ s16x8 cvt8(float4 lo, float4 hi) {
    union { s16x8 v; __hip_bfloat162 h[4]; } u;
    u.h[0] = __float22bfloat162_rn(make_float2(lo.x, lo.y));
    u.h[1] = __float22bfloat162_rn(make_float2(lo.z, lo.w));
    u.h[2] = __float22bfloat162_rn(make_float2(hi.x, hi.y));
    u.h[3] = __float22bfloat162_rn(make_float2(hi.z, hi.w));
    return u.v;
}

// ---- weight prep: WT[g][n][k] = bf16(W_g[k][n]), g in {src, tgt, edge} ----
__global__ void kprep(const float* __restrict__ Wsrc, const float* __restrict__ Wtgt,
                      const float* __restrict__ Wedge, u16* __restrict__ WT) {
    int i = blockIdx.x * 256 + threadIdx.x;
    if (i >= 3 * 16384) return;
    int g = i >> 14, nk = i & 16383, n = nk >> 7, k = nk & 127;
    const float* W = (g == 0) ? Wsrc : (g == 1) ? Wtgt : Wedge;
    WT[i] = (u16)f2bf(W[k * 128 + n]);
}

// ---- K1: R15 staging/phase pipeline + 2M x 2N wave split.
// Each wave: 32 rows x 64 cols -> 24 ds_read_b128/phase (vs 36), same 32 MFMA.
// LDS read traffic per CU per phase: 432 KB -> 288 KB. ----
__global__ __launch_bounds__(256, 2) void k1(
    const float* __restrict__ recv, const float* __restrict__ send,
    const float* __restrict__ eattr, const int* __restrict__ sidx,
    const u16* __restrict__ WT, const float* __restrict__ attn,
    float* __restrict__ ez, float* __restrict__ denom)
{
    __shared__ u16 ldsA[64][136];      // 17408 B
    __shared__ u16 ldsB[128][136];     // 34816 B
    __shared__ float smEz[64][4];      // 1 KB, block-shared
    const int tid = threadIdx.x;
    const int lane = tid & 63, wv = tid >> 6;
    const int l15 = lane & 15, lg = (lane >> 4) & 3;
    const int wm = wv >> 1, wn = wv & 1;   // 2 waves in M x 2 in N
    const int row0 = blockIdx.x * 64;

    const float* Xg[3] = {send, eattr, recv};
    const int bgoff[3] = {0, 2 * 16384, 1 * 16384};  // Wsrc, Wedge, Wtgt

    f32x4 acc[2][4];
#pragma unroll
    for (int m = 0; m < 2; ++m)
#pragma unroll
        for (int ni = 0; ni < 4; ++ni) acc[m][ni] = (f32x4){0.f, 0.f, 0.f, 0.f};

    float4 ra[4][2];   // in-flight A (32 VGPR)

    auto issueA = [&](int g) {
        const float* X = Xg[g];
#pragma unroll
        for (int q = 0; q < 4; ++q) {
            int idx = tid + 256 * q;                 // 0..1023
            int row = idx >> 4, gcol = (idx & 15) * 8;
            int ge = min(row0 + row, E_EDGES - 1);
            const float* p = X + (size_t)ge * 128 + gcol;
            ra[q][0] = *(const float4*)p;
            ra[q][1] = *(const float4*)(p + 4);
        }
    };

    auto commitA = [&]() {
#pragma unroll
        for (int q = 0; q < 4; ++q) {
            int idx = tid + 256 * q;
            *(s16x8*)&ldsA[idx >> 4][(idx & 15) * 8] = cvt8(ra[q][0], ra[q][1]);
        }
    };

    auto mfma_g = [&]() {
#pragma unroll
        for (int kk = 0; kk < 4; ++kk) {
            int k0 = kk * 32 + lg * 8;
            s16x8 a0 = *(const s16x8*)&ldsA[wm * 32 + l15][k0];
            s16x8 a1 = *(const s16x8*)&ldsA[wm * 32 + 16 + l15][k0];
#pragma unroll
            for (int ni = 0; ni < 4; ++ni) {
                s16x8 b = *(const s16x8*)&ldsB[(wn * 4 + ni) * 16 + l15][k0];
                acc[0][ni] = __builtin_amdgcn_mfma_f32_16x16x32_bf16(a0, b, acc[0][ni], 0, 0, 0);
                acc[1][ni] = __builtin_amdgcn_mfma_f32_16x16x32_bf16(a1, b, acc[1][ni], 0, 0, 0);
            }
        }
    };

    issueA(0);
#pragma unroll
    for (int g = 0; g < 3; ++g) {
        if (g) { mfma_g(); SCHED0(); }      // compute g-1 while A(g) streams in
        BAR();                               // all waves done reading LDS(g-1)
        s16x8 rb[8];
        {
            const u16* Bg = WT + bgoff[g];
#pragma unroll
            for (int q = 0; q < 8; ++q) {
                int idx = tid + 256 * q;
                rb[q] = *(const s16x8*)(Bg + (idx >> 4) * 128 + (idx & 15) * 8);
            }
        }
        commitA();                           // drains this phase's A
        if (g < 2) issueA(g + 1);            // queue next stream behind the drain
        SCHED0();
#pragma unroll
        for (int q = 0; q < 8; ++q) {
            int idx = tid + 256 * q;
            *(s16x8*)&ldsB[idx >> 4][(idx & 15) * 8] = rb[q];
        }
        SCHED0();
        WAITLGKM0();
        BAR();
    }
    mfma_g();                                // g = 2

    // attn coeffs for this wave's 4 n-frags (abs frag = wn*4 + ni)
    float av[4];
#pragma unroll
    for (int ni = 0; ni < 4; ++ni) av[ni] = attn[(wn * 4 + ni) * 16 + l15];

    // reduce z for this wave's two heads (h = 2*wn + hh)
#pragma unroll
    for (int m = 0; m < 2; ++m) {
#pragma unroll
        for (int hh = 0; hh < 2; ++hh) {
            float part[4];
#pragma unroll
            for (int j = 0; j < 4; ++j)
                part[j] = lrelu(acc[m][2 * hh][j]) * av[2 * hh] +
                          lrelu(acc[m][2 * hh + 1][j]) * av[2 * hh + 1];
#pragma unroll
            for (int off = 1; off < 16; off <<= 1) {
#pragma unroll
                for (int j = 0; j < 4; ++j) part[j] += __shfl_xor(part[j], off, 64);
            }
            if (l15 == hh) {
#pragma unroll
                for (int j = 0; j < 4; ++j)
                    smEz[wm * 32 + m * 16 + lg * 4 + j][2 * wn + hh] = __expf(part[j]);
            }
        }
    }
    __syncthreads();   // smEz written by all 4 waves
    // tid -> (row = tid>>2, head = tid&3): 1 KB fully-coalesced ez store
    {
        int row = tid >> 2, h = tid & 3;
        int r = row0 + row;
        float v = smEz[row][h];
        if (r < E_EDGES) {
            ez[(size_t)r * 4 + h] = v;
            int s = sidx[r];
            atomicAdd(&denom[(size_t)s * 4 + h], v);
        }
    }
}

// ---- K2: champion structure unchanged (ldsA+ldsB, one sync), a = ez/denom fused ----
__global__ __launch_bounds__(256, 2) void k2(
    const float* __restrict__ recv, const int* __restrict__ ridx,
    const int* __restrict__ sidx, const u16* __restrict__ WTt,
    const float* __restrict__ ez, const float* __restrict__ denom,
    float* __restrict__ out0, float* __restrict__ out1)
{
    __shared__ u16 ldsA[128][136];
    __shared__ u16 ldsB[128][136];
    int tid = threadIdx.x;
    int lane = tid & 63, wv = tid >> 6;
    int l15 = lane & 15, lg = lane >> 4;
    int blockRow = blockIdx.x * 128;

    f32x4 acc[2][8];
#pragma unroll
    for (int m = 0; m < 2; ++m)
#pragma unroll
        for (int n = 0; n < 8; ++n) acc[m][n] = (f32x4){0.f, 0.f, 0.f, 0.f};

#pragma unroll
    for (int it = 0; it < 8; ++it) {
        int chunk = it * 256 + tid;
        int row = chunk >> 4, kc = (chunk & 15) << 3;
        int ge = min(blockRow + row, E_EDGES - 1);
        const float* p = recv + (size_t)ge * 128 + kc;
        float4 v0 = *(const float4*)p;
        float4 v1 = *(const float4*)(p + 4);
        *(s16x8*)&ldsA[row][kc] = cvt8(v0, v1);
    }
#pragma unroll
    for (int it = 0; it < 8; ++it) {
        int chunk = it * 256 + tid;
        int n = chunk >> 4, kc = (chunk & 15) << 3;
        *(s16x8*)&ldsB[n][kc] = *(const s16x8*)(WTt + n * 128 + kc);
    }
    __syncthreads();

#pragma unroll
    for (int kk = 0; kk < 4; ++kk) {
        int k0 = kk * 32 + lg * 8;
        s16x8 a0 = *(const s16x8*)&ldsA[wv * 32 + l15][k0];
        s16x8 a1 = *(const s16x8*)&ldsA[wv * 32 + 16 + l15][k0];
#pragma unroll
        for (int n = 0; n < 8; ++n) {
            s16x8 b = *(const s16x8*)&ldsB[n * 16 + l15][k0];
            acc[0][n] = __builtin_amdgcn_mfma_f32_16x16x32_bf16(a0, b, acc[0][n], 0, 0, 0);
            acc[1][n] = __builtin_amdgcn_mfma_f32_16x16x32_bf16(a1, b, acc[1][n], 0, 0, 0);
        }
    }

#pragma unroll
    for (int m = 0; m < 2; ++m) {
#pragma unroll
        for (int j = 0; j < 4; ++j) {
            int r = blockRow + wv * 32 + m * 16 + lg * 4 + j;
            if (r < E_EDGES) {
                int s = sidx[r];
                float4 ezv = *(const float4*)(ez + (size_t)r * 4);
                float4 dn = *(const float4*)(denom + (size_t)s * 4);
                float a0 = ezv.x / dn.x, a1 = ezv.y / dn.y;
                float a2 = ezv.z / dn.z, a3 = ezv.w / dn.w;
                float lo = 0.25f * (acc[m][0][j] * a0 + acc[m][2][j] * a1 +
                                    acc[m][4][j] * a2 + acc[m][6][j] * a3);
                float hi = 0.25f * (acc[m][1][j] * a0 + acc[m][3][j] * a1 +
                                    acc[m][5][j] * a2 + acc[m][7][j] * a3);
                out1[(size_t)r * 32 + l15] = lo;
                out1[(size_t)r * 32 + 16 + l15] = hi;
                int rv = ridx[r];
                atomicAdd(&out0[(size_t)rv * 32 + l15], lo);
                atomicAdd(&out0[(size_t)rv * 32 + 16 + l15], hi);
            }
        }
    }
}

extern "C" void kernel_launch(void* const* d_in, const int* in_sizes, int n_in,
                              void* d_out, int out_size, void* d_ws, size_t ws_size,
                              hipStream_t stream) {
    const float* recv  = (const float*)d_in[0];
    const float* send  = (const float*)d_in[1];
    const float* eattr = (const float*)d_in[2];
    const int*   sidx  = (const int*)d_in[3];
    const int*   ridx  = (const int*)d_in[4];
    const float* Wsrc  = (const float*)d_in[5];
    const float* Wtgt  = (const float*)d_in[6];
    const float* Wedge = (const float*)d_in[7];
    const float* attn  = (const float*)d_in[8];

    char* ws = (char*)d_ws;
    u16*   WT    = (u16*)ws;                         // 98304 B
    float* ez    = (float*)(ws + 131072);            // 8,000,000 B
    float* denom = (float*)(ws + 131072 + 8000000);  // 800,000 B

    float* out0 = (float*)d_out;                     // [N,32]
    float* out1 = out0 + (size_t)NN * 32;            // [E,32]

    hipMemsetAsync(denom, 0, (size_t)NN * 4 * sizeof(float), stream);
    hipMemsetAsync(out0, 0, (size_t)NN * 32 * sizeof(float), stream);

    kprep<<<192, 256, 0, stream>>>(Wsrc, Wtgt, Wedge, WT);

    int nb1 = (E_EDGES + 63) / 64;    // 7813
    int nb2 = (E_EDGES + 127) / 128;  // 3907
    k1<<<nb1, 256, 0, stream>>>(recv, send, eattr, sidx, WT, attn, ez, denom);
    k2<<<nb2, 256, 0, stream>>>(recv, ridx, sidx, WT + 16384, ez, denom, out0, out1);
}

// Round 17
// 283.605 us; speedup vs baseline: 1.9907x; 1.0573x over previous
//
#include <hip/hip_runtime.h>
#include <hip/hip_bf16.h>

#define E_EDGES 500000
#define NN 50000

typedef unsigned short u16;
typedef __attribute__((ext_vector_type(8))) short s16x8;
typedef __attribute__((ext_vector_type(4))) float f32x4;

#define BAR() __builtin_amdgcn_s_barrier()
#define SCHED0() __builtin_amdgcn_sched_barrier(0)
#define WAITLGKM0() asm volatile("s_waitcnt lgkmcnt(0)" ::: "memory")

__device__ __forceinline__ short f2bf(float f) {
    unsigned u = __builtin_bit_cast(unsigned, f);
    u += 0x7fffu + ((u >> 16) & 1u);
    return (short)(u >> 16);
}

__device__ __forceinline__ float lrelu(float x) { return x > 0.0f ? x : 0.01f * x; }

// packed fp32x8 -> bf16x8 via v_cvt_pk_bf16_f32
__device__ __forceinline__ s16x8 cvt8(float4 lo, float4 hi) {
    union { s16x8 v; __hip_bfloat162 h[4]; } u;
    u.h[0] = __float22bfloat162_rn(make_float2(lo.x, lo.y));
    u.h[1] = __float22bfloat162_rn(make_float2(lo.z, lo.w));
    u.h[2] = __float22bfloat162_rn(make_float2(hi.x, hi.y));
    u.h[3] = __float22bfloat162_rn(make_float2(hi.z, hi.w));
    return u.v;
}

// ---- weight prep: WT[g][n][k] = bf16(W_g[k][n]), g in {src, tgt, edge} ----
__global__ void kprep(const float* __restrict__ Wsrc, const float* __restrict__ Wtgt,
                      const float* __restrict__ Wedge, u16* __restrict__ WT) {
    int i = blockIdx.x * 256 + threadIdx.x;
    if (i >= 3 * 16384) return;
    int g = i >> 14, nk = i & 16383, n = nk >> 7, k = nk & 127;
    const float* W = (g == 0) ? Wsrc : (g == 1) ? Wtgt : Wedge;
    WT[i] = (u16)f2bf(W[k * 128 + n]);
}

// ---- K1: R16 champion, byte-identical. ----
__global__ __launch_bounds__(256, 2) void k1(
    const float* __restrict__ recv, const float* __restrict__ send,
    const float* __restrict__ eattr, const int* __restrict__ sidx,
    const u16* __restrict__ WT, const float* __restrict__ attn,
    float* __restrict__ ez, float* __restrict__ denom)
{
    __shared__ u16 ldsA[64][136];      // 17408 B
    __shared__ u16 ldsB[128][136];     // 34816 B
    __shared__ float smEz[64][4];      // 1 KB, block-shared
    const int tid = threadIdx.x;
    const int lane = tid & 63, wv = tid >> 6;
    const int l15 = lane & 15, lg = (lane >> 4) & 3;
    const int wm = wv >> 1, wn = wv & 1;   // 2 waves in M x 2 in N
    const int row0 = blockIdx.x * 64;

    const float* Xg[3] = {send, eattr, recv};
    const int bgoff[3] = {0, 2 * 16384, 1 * 16384};  // Wsrc, Wedge, Wtgt

    f32x4 acc[2][4];
#pragma unroll
    for (int m = 0; m < 2; ++m)
#pragma unroll
        for (int ni = 0; ni < 4; ++ni) acc[m][ni] = (f32x4){0.f, 0.f, 0.f, 0.f};

    float4 ra[4][2];   // in-flight A (32 VGPR)

    auto issueA = [&](int g) {
        const float* X = Xg[g];
#pragma unroll
        for (int q = 0; q < 4; ++q) {
            int idx = tid + 256 * q;                 // 0..1023
            int row = idx >> 4, gcol = (idx & 15) * 8;
            int ge = min(row0 + row, E_EDGES - 1);
            const float* p = X + (size_t)ge * 128 + gcol;
            ra[q][0] = *(const float4*)p;
            ra[q][1] = *(const float4*)(p + 4);
        }
    };

    auto commitA = [&]() {
#pragma unroll
        for (int q = 0; q < 4; ++q) {
            int idx = tid + 256 * q;
            *(s16x8*)&ldsA[idx >> 4][(idx & 15) * 8] = cvt8(ra[q][0], ra[q][1]);
        }
    };

    auto mfma_g = [&]() {
#pragma unroll
        for (int kk = 0; kk < 4; ++kk) {
            int k0 = kk * 32 + lg * 8;
            s16x8 a0 = *(const s16x8*)&ldsA[wm * 32 + l15][k0];
            s16x8 a1 = *(const s16x8*)&ldsA[wm * 32 + 16 + l15][k0];
#pragma unroll
            for (int ni = 0; ni < 4; ++ni) {
                s16x8 b = *(const s16x8*)&ldsB[(wn * 4 + ni) * 16 + l15][k0];
                acc[0][ni] = __builtin_amdgcn_mfma_f32_16x16x32_bf16(a0, b, acc[0][ni], 0, 0, 0);
                acc[1][ni] = __builtin_amdgcn_mfma_f32_16x16x32_bf16(a1, b, acc[1][ni], 0, 0, 0);
            }
        }
    };

    issueA(0);
#pragma unroll
    for (int g = 0; g < 3; ++g) {
        if (g) { mfma_g(); SCHED0(); }      // compute g-1 while A(g) streams in
        BAR();                               // all waves done reading LDS(g-1)
        s16x8 rb[8];
        {
            const u16* Bg = WT + bgoff[g];
#pragma unroll
            for (int q = 0; q < 8; ++q) {
                int idx = tid + 256 * q;
                rb[q] = *(const s16x8*)(Bg + (idx >> 4) * 128 + (idx & 15) * 8);
            }
        }
        commitA();                           // drains this phase's A
        if (g < 2) issueA(g + 1);            // queue next stream behind the drain
        SCHED0();
#pragma unroll
        for (int q = 0; q < 8; ++q) {
            int idx = tid + 256 * q;
            *(s16x8*)&ldsB[idx >> 4][(idx & 15) * 8] = rb[q];
        }
        SCHED0();
        WAITLGKM0();
        BAR();
    }
    mfma_g();                                // g = 2

    float av[4];
#pragma unroll
    for (int ni = 0; ni < 4; ++ni) av[ni] = attn[(wn * 4 + ni) * 16 + l15];

#pragma unroll
    for (int m = 0; m < 2; ++m) {
#pragma unroll
        for (int hh = 0; hh < 2; ++hh) {
            float part[4];
#pragma unroll
            for (int j = 0; j < 4; ++j)
                part[j] = lrelu(acc[m][2 * hh][j]) * av[2 * hh] +
                          lrelu(acc[m][2 * hh + 1][j]) * av[2 * hh + 1];
#pragma unroll
            for (int off = 1; off < 16; off <<= 1) {
#pragma unroll
                for (int j = 0; j < 4; ++j) part[j] += __shfl_xor(part[j], off, 64);
            }
            if (l15 == hh) {
#pragma unroll
                for (int j = 0; j < 4; ++j)
                    smEz[wm * 32 + m * 16 + lg * 4 + j][2 * wn + hh] = __expf(part[j]);
            }
        }
    }
    __syncthreads();   // smEz written by all 4 waves
    {
        int row = tid >> 2, h = tid & 3;
        int r = row0 + row;
        float v = smEz[row][h];
        if (r < E_EDGES) {
            ez[(size_t)r * 4 + h] = v;
            int s = sidx[r];
            atomicAdd(&denom[(size_t)s * 4 + h], v);
        }
    }
}

// ---- K2: M=64 tile, 3 blocks/CU (52.2 KB LDS), reg-batched issue, one sync.
// a = ez/denom fused; epilogue unchanged. ----
__global__ __launch_bounds__(256, 2) void k2(
    const float* __restrict__ recv, const int* __restrict__ ridx,
    const int* __restrict__ sidx, const u16* __restrict__ WTt,
    const float* __restrict__ ez, const float* __restrict__ denom,
    float* __restrict__ out0, float* __restrict__ out1)
{
    __shared__ u16 ldsA[64][136];      // 17408 B
    __shared__ u16 ldsB[128][136];     // 34816 B
    const int tid = threadIdx.x;
    const int lane = tid & 63, wv = tid >> 6;   // 4 waves x 16 rows
    const int l15 = lane & 15, lg = (lane >> 4) & 3;
    const int row0 = blockIdx.x * 64;

    // issue A (64 rows x 16 granules = 1024 chunks, 4/thread) and B (8/thread)
    float4 ra[4][2];
#pragma unroll
    for (int q = 0; q < 4; ++q) {
        int idx = tid + 256 * q;
        int row = idx >> 4, gcol = (idx & 15) * 8;
        int ge = min(row0 + row, E_EDGES - 1);
        const float* p = recv + (size_t)ge * 128 + gcol;
        ra[q][0] = *(const float4*)p;
        ra[q][1] = *(const float4*)(p + 4);
    }
    s16x8 rb[8];
#pragma unroll
    for (int q = 0; q < 8; ++q) {
        int idx = tid + 256 * q;
        rb[q] = *(const s16x8*)(WTt + (idx >> 4) * 128 + (idx & 15) * 8);
    }
#pragma unroll
    for (int q = 0; q < 4; ++q) {
        int idx = tid + 256 * q;
        *(s16x8*)&ldsA[idx >> 4][(idx & 15) * 8] = cvt8(ra[q][0], ra[q][1]);
    }
#pragma unroll
    for (int q = 0; q < 8; ++q) {
        int idx = tid + 256 * q;
        *(s16x8*)&ldsB[idx >> 4][(idx & 15) * 8] = rb[q];
    }
    __syncthreads();

    f32x4 acc[8];
#pragma unroll
    for (int n = 0; n < 8; ++n) acc[n] = (f32x4){0.f, 0.f, 0.f, 0.f};

#pragma unroll
    for (int kk = 0; kk < 4; ++kk) {
        int k0 = kk * 32 + lg * 8;
        s16x8 a = *(const s16x8*)&ldsA[wv * 16 + l15][k0];
#pragma unroll
        for (int n = 0; n < 8; ++n) {
            s16x8 b = *(const s16x8*)&ldsB[n * 16 + l15][k0];
            acc[n] = __builtin_amdgcn_mfma_f32_16x16x32_bf16(a, b, acc[n], 0, 0, 0);
        }
    }

#pragma unroll
    for (int j = 0; j < 4; ++j) {
        int r = row0 + wv * 16 + lg * 4 + j;
        if (r < E_EDGES) {
            int s = sidx[r];
            float4 ezv = *(const float4*)(ez + (size_t)r * 4);
            float4 dn = *(const float4*)(denom + (size_t)s * 4);
            float a0 = ezv.x / dn.x, a1 = ezv.y / dn.y;
            float a2 = ezv.z / dn.z, a3 = ezv.w / dn.w;
            float lo = 0.25f * (acc[0][j] * a0 + acc[2][j] * a1 +
                                acc[4][j] * a2 + acc[6][j] * a3);
            float hi = 0.25f * (acc[1][j] * a0 + acc[3][j] * a1 +
                                acc[5][j] * a2 + acc[7][j] * a3);
            out1[(size_t)r * 32 + l15] = lo;
            out1[(size_t)r * 32 + 16 + l15] = hi;
            int rv = ridx[r];
            atomicAdd(&out0[(size_t)rv * 32 + l15], lo);
            atomicAdd(&out0[(size_t)rv * 32 + 16 + l15], hi);
        }
    }
}

extern "C" void kernel_launch(void* const* d_in, const int* in_sizes, int n_in,
                              void* d_out, int out_size, void* d_ws, size_t ws_size,
                              hipStream_t stream) {
    const float* recv  = (const float*)d_in[0];
    const float* send  = (const float*)d_in[1];
    const float* eattr = (const float*)d_in[2];
    const int*   sidx  = (const int*)d_in[3];
    const int*   ridx  = (const int*)d_in[4];
    const float* Wsrc  = (const float*)d_in[5];
    const float* Wtgt  = (const float*)d_in[6];
    const float* Wedge = (const float*)d_in[7];
    const float* attn  = (const float*)d_in[8];

    char* ws = (char*)d_ws;
    u16*   WT    = (u16*)ws;                         // 98304 B
    float* ez    = (float*)(ws + 131072);            // 8,000,000 B
    float* denom = (float*)(ws + 131072 + 8000000);  // 800,000 B

    float* out0 = (float*)d_out;                     // [N,32]
    float* out1 = out0 + (size_t)NN * 32;            // [E,32]

    hipMemsetAsync(denom, 0, (size_t)NN * 4 * sizeof(float), stream);
    hipMemsetAsync(out0, 0, (size_t)NN * 32 * sizeof(float), stream);

    kprep<<<192, 256, 0, stream>>>(Wsrc, Wtgt, Wedge, WT);

    int nb = (E_EDGES + 63) / 64;    // 7813
    k1<<<nb, 256, 0, stream>>>(recv, send, eattr, sidx, WT, attn, ez, denom);
    k2<<<nb, 256, 0, stream>>>(recv, ridx, sidx, WT + 16384, ez, denom, out0, out1);
}

// Round 18
// 275.831 us; speedup vs baseline: 2.0468x; 1.0282x over previous
//
#include <hip/hip_runtime.h>
#include <hip/hip_bf16.h>

#define E_EDGES 500000
#define NN 50000

typedef unsigned short u16;
typedef __attribute__((ext_vector_type(8))) short s16x8;
typedef __attribute__((ext_vector_type(4))) float f32x4;

#define BAR() __builtin_amdgcn_s_barrier()
#define SCHED0() __builtin_amdgcn_sched_barrier(0)
#define WAITLGKM0() asm volatile("s_waitcnt lgkmcnt(0)" ::: "memory")

__device__ __forceinline__ short f2bf(float f) {
    unsigned u = __builtin_bit_cast(unsigned, f);
    u += 0x7fffu + ((u >> 16) & 1u);
    return (short)(u >> 16);
}

__device__ __forceinline__ float lrelu(float x) { return x > 0.0f ? x : 0.01f * x; }

// packed fp32x8 -> bf16x8 via v_cvt_pk_bf16_f32
__device__ __forceinline__ s16x8 cvt8(float4 lo, float4 hi) {
    union { s16x8 v; __hip_bfloat162 h[4]; } u;
    u.h[0] = __float22bfloat162_rn(make_float2(lo.x, lo.y));
    u.h[1] = __float22bfloat162_rn(make_float2(lo.z, lo.w));
    u.h[2] = __float22bfloat162_rn(make_float2(hi.x, hi.y));
    u.h[3] = __float22bfloat162_rn(make_float2(hi.z, hi.w));
    return u.v;
}

// ---- weight prep: WT[g][n][k] = bf16(W_g[k][n]), g in {src, tgt, edge} ----
__global__ void kprep(const float* __restrict__ Wsrc, const float* __restrict__ Wtgt,
                      const float* __restrict__ Wedge, u16* __restrict__ WT) {
    int i = blockIdx.x * 256 + threadIdx.x;
    if (i >= 3 * 16384) return;
    int g = i >> 14, nk = i & 16383, n = nk >> 7, k = nk & 127;
    const float* W = (g == 0) ? Wsrc : (g == 1) ? Wtgt : Wedge;
    WT[i] = (u16)f2bf(W[k * 128 + n]);
}

// ---- K1: B resident in VGPRs (96 regs, loaded once), 1M x 4N wave split
// (wave wv owns head wv = n-frags {2wv, 2wv+1}, all 64 rows).
// ~8 interleaved tiles per block (tile = b + i*1024) amortize the B load and
// keep the device-wide read band compact (R13 lesson). Per phase: only
// 4 A-loads + 4 ds_writes + 16 ds_reads + 32 MFMA per wave. ----
__global__ __launch_bounds__(256, 2) void k1(
    const float* __restrict__ recv, const float* __restrict__ send,
    const float* __restrict__ eattr, const int* __restrict__ sidx,
    const u16* __restrict__ WT, const float* __restrict__ attn,
    float* __restrict__ ez, float* __restrict__ denom)
{
    __shared__ u16 ldsA[64][136];      // 17408 B
    __shared__ float smEz[64][4];      // 1 KB
    const int tid = threadIdx.x;
    const int lane = tid & 63, wv = tid >> 6;
    const int l15 = lane & 15, lg = (lane >> 4) & 3;
    const int b = blockIdx.x;

    const float* Xg[3] = {send, eattr, recv};
    const int bgoff[3] = {0, 2 * 16384, 1 * 16384};  // Wsrc, Wedge, Wtgt

    // B fragments resident in VGPR: bfr[g][kk][nn]; nfrag = 2*wv + nn
    s16x8 bfr[3][4][2];
#pragma unroll
    for (int g = 0; g < 3; ++g)
#pragma unroll
        for (int kk = 0; kk < 4; ++kk)
#pragma unroll
            for (int nn = 0; nn < 2; ++nn)
                bfr[g][kk][nn] = *(const s16x8*)(WT + bgoff[g] +
                    ((wv * 2 + nn) * 16 + l15) * 128 + kk * 32 + lg * 8);

    const float av0 = attn[(wv * 2 + 0) * 16 + l15];
    const float av1 = attn[(wv * 2 + 1) * 16 + l15];

    f32x4 acc[4][2];
    float4 ra[4][2];

    auto issueA = [&](const float* X, int tileRow) {
#pragma unroll
        for (int q = 0; q < 4; ++q) {
            int idx = tid + 256 * q;                 // 0..1023
            int row = idx >> 4, gcol = (idx & 15) * 8;
            int ge = min(tileRow + row, E_EDGES - 1);
            const float* p = X + (size_t)ge * 128 + gcol;
            ra[q][0] = *(const float4*)p;
            ra[q][1] = *(const float4*)(p + 4);
        }
    };

    auto commitA = [&]() {
#pragma unroll
        for (int q = 0; q < 4; ++q) {
            int idx = tid + 256 * q;
            *(s16x8*)&ldsA[idx >> 4][(idx & 15) * 8] = cvt8(ra[q][0], ra[q][1]);
        }
    };

    auto mfma_ph = [&](const s16x8 (&bf)[4][2]) {
#pragma unroll
        for (int kk = 0; kk < 4; ++kk) {
            int k0 = kk * 32 + lg * 8;
#pragma unroll
            for (int m = 0; m < 4; ++m) {
                s16x8 a = *(const s16x8*)&ldsA[m * 16 + l15][k0];
                acc[m][0] = __builtin_amdgcn_mfma_f32_16x16x32_bf16(a, bf[kk][0], acc[m][0], 0, 0, 0);
                acc[m][1] = __builtin_amdgcn_mfma_f32_16x16x32_bf16(a, bf[kk][1], acc[m][1], 0, 0, 0);
            }
        }
    };

    const int nt = (b < 645) ? 8 : 7;   // 7813 tiles over 1024 blocks, interleaved
    issueA(Xg[0], b * 64);

    for (int i = 0; i < nt; ++i) {
        const int tile = b + i * 1024;
        const int row0 = tile * 64;

#pragma unroll
        for (int m = 0; m < 4; ++m)
#pragma unroll
            for (int nn = 0; nn < 2; ++nn) acc[m][nn] = (f32x4){0.f, 0.f, 0.f, 0.f};

#pragma unroll
        for (int g = 0; g < 3; ++g) {
            if (g == 1) { mfma_ph(bfr[0]); SCHED0(); }
            if (g == 2) { mfma_ph(bfr[1]); SCHED0(); }
            BAR();                               // all waves done reading prev ldsA
            commitA();                           // vmcnt wait + cvt + ds_write
            if (g < 2) issueA(Xg[g + 1], row0);  // queue next stream behind drain
            else if (i + 1 < nt) issueA(Xg[0], row0 + 65536);  // next tile (+1024*64)
            SCHED0();
            WAITLGKM0();                         // ds_writes drained
            BAR();
        }
        mfma_ph(bfr[2]);                         // phase 2; next tile's loads in flight

        // epilogue: z for head wv over this wave's 64 rows
#pragma unroll
        for (int m = 0; m < 4; ++m) {
            float part[4];
#pragma unroll
            for (int j = 0; j < 4; ++j)
                part[j] = lrelu(acc[m][0][j]) * av0 + lrelu(acc[m][1][j]) * av1;
#pragma unroll
            for (int off = 1; off < 16; off <<= 1) {
#pragma unroll
                for (int j = 0; j < 4; ++j) part[j] += __shfl_xor(part[j], off, 64);
            }
            if (l15 == 0) {
#pragma unroll
                for (int j = 0; j < 4; ++j)
                    smEz[m * 16 + lg * 4 + j][wv] = __expf(part[j]);
            }
        }
        __syncthreads();   // smEz complete; also fences ldsA reads before next commit
        {
            int row = tid >> 2, h = tid & 3;
            int r = row0 + row;
            float v = smEz[row][h];
            if (r < E_EDGES) {
                ez[(size_t)r * 4 + h] = v;
                int s = sidx[r];
                atomicAdd(&denom[(size_t)s * 4 + h], v);
            }
        }
    }
}

// ---- K2: R17 proven structure (M=64, 3 blocks/CU, one sync), a = ez/denom fused ----
__global__ __launch_bounds__(256, 2) void k2(
    const float* __restrict__ recv, const int* __restrict__ ridx,
    const int* __restrict__ sidx, const u16* __restrict__ WTt,
    const float* __restrict__ ez, const float* __restrict__ denom,
    float* __restrict__ out0, float* __restrict__ out1)
{
    __shared__ u16 ldsA[64][136];      // 17408 B
    __shared__ u16 ldsB[128][136];     // 34816 B
    const int tid = threadIdx.x;
    const int lane = tid & 63, wv = tid >> 6;   // 4 waves x 16 rows
    const int l15 = lane & 15, lg = (lane >> 4) & 3;
    const int row0 = blockIdx.x * 64;

    float4 ra[4][2];
#pragma unroll
    for (int q = 0; q < 4; ++q) {
        int idx = tid + 256 * q;
        int row = idx >> 4, gcol = (idx & 15) * 8;
        int ge = min(row0 + row, E_EDGES - 1);
        const float* p = recv + (size_t)ge * 128 + gcol;
        ra[q][0] = *(const float4*)p;
        ra[q][1] = *(const float4*)(p + 4);
    }
    s16x8 rb[8];
#pragma unroll
    for (int q = 0; q < 8; ++q) {
        int idx = tid + 256 * q;
        rb[q] = *(const s16x8*)(WTt + (idx >> 4) * 128 + (idx & 15) * 8);
    }
#pragma unroll
    for (int q = 0; q < 4; ++q) {
        int idx = tid + 256 * q;
        *(s16x8*)&ldsA[idx >> 4][(idx & 15) * 8] = cvt8(ra[q][0], ra[q][1]);
    }
#pragma unroll
    for (int q = 0; q < 8; ++q) {
        int idx = tid + 256 * q;
        *(s16x8*)&ldsB[idx >> 4][(idx & 15) * 8] = rb[q];
    }
    __syncthreads();

    f32x4 acc[8];
#pragma unroll
    for (int n = 0; n < 8; ++n) acc[n] = (f32x4){0.f, 0.f, 0.f, 0.f};

#pragma unroll
    for (int kk = 0; kk < 4; ++kk) {
        int k0 = kk * 32 + lg * 8;
        s16x8 a = *(const s16x8*)&ldsA[wv * 16 + l15][k0];
#pragma unroll
        for (int n = 0; n < 8; ++n) {
            s16x8 b = *(const s16x8*)&ldsB[n * 16 + l15][k0];
            acc[n] = __builtin_amdgcn_mfma_f32_16x16x32_bf16(a, b, acc[n], 0, 0, 0);
        }
    }

#pragma unroll
    for (int j = 0; j < 4; ++j) {
        int r = row0 + wv * 16 + lg * 4 + j;
        if (r < E_EDGES) {
            int s = sidx[r];
            float4 ezv = *(const float4*)(ez + (size_t)r * 4);
            float4 dn = *(const float4*)(denom + (size_t)s * 4);
            float a0 = ezv.x / dn.x, a1 = ezv.y / dn.y;
            float a2 = ezv.z / dn.z, a3 = ezv.w / dn.w;
            float lo = 0.25f * (acc[0][j] * a0 + acc[2][j] * a1 +
                                acc[4][j] * a2 + acc[6][j] * a3);
            float hi = 0.25f * (acc[1][j] * a0 + acc[3][j] * a1 +
                                acc[5][j] * a2 + acc[7][j] * a3);
            out1[(size_t)r * 32 + l15] = lo;
            out1[(size_t)r * 32 + 16 + l15] = hi;
            int rv = ridx[r];
            atomicAdd(&out0[(size_t)rv * 32 + l15], lo);
            atomicAdd(&out0[(size_t)rv * 32 + 16 + l15], hi);
        }
    }
}

extern "C" void kernel_launch(void* const* d_in, const int* in_sizes, int n_in,
                              void* d_out, int out_size, void* d_ws, size_t ws_size,
                              hipStream_t stream) {
    const float* recv  = (const float*)d_in[0];
    const float* send  = (const float*)d_in[1];
    const float* eattr = (const float*)d_in[2];
    const int*   sidx  = (const int*)d_in[3];
    const int*   ridx  = (const int*)d_in[4];
    const float* Wsrc  = (const float*)d_in[5];
    const float* Wtgt  = (const float*)d_in[6];
    const float* Wedge = (const float*)d_in[7];
    const float* attn  = (const float*)d_in[8];

    char* ws = (char*)d_ws;
    u16*   WT    = (u16*)ws;                         // 98304 B
    float* ez    = (float*)(ws + 131072);            // 8,000,000 B
    float* denom = (float*)(ws + 131072 + 8000000);  // 800,000 B

    float* out0 = (float*)d_out;                     // [N,32]
    float* out1 = out0 + (size_t)NN * 32;            // [E,32]

    hipMemsetAsync(denom, 0, (size_t)NN * 4 * sizeof(float), stream);
    hipMemsetAsync(out0, 0, (size_t)NN * 32 * sizeof(float), stream);

    kprep<<<192, 256, 0, stream>>>(Wsrc, Wtgt, Wedge, WT);

    k1<<<1024, 256, 0, stream>>>(recv, send, eattr, sidx, WT, attn, ez, denom);
    int nb2 = (E_EDGES + 63) / 64;   // 7813
    k2<<<nb2, 256, 0, stream>>>(recv, ridx, sidx, WT + 16384, ez, denom, out0, out1);
}